// Round 7
// baseline (656.509 us; speedup 1.0000x reference)
//
#include <hip/hip_runtime.h>

#define N_PTS 131072
#define TD 4096
#define DD 64
#define KK 1024
#define MARGIN_TH 2e-3f

typedef short bf16x8 __attribute__((ext_vector_type(8)));
typedef float f32x4  __attribute__((ext_vector_type(4)));

__device__ inline unsigned short f2bf(float f) {           // RNE float->bf16
    unsigned u = __float_as_uint(f);
    unsigned r = u + 0x7FFFu + ((u >> 16) & 1u);
    return (unsigned short)(r >> 16);
}
__device__ inline float bf2f(unsigned short h) {
    return __uint_as_float(((unsigned)h) << 16);
}

// ---------------- K0a: transpose z[B,D,T] -> z_hi/z_lo bf16 [N,D] ----------------
__global__ __launch_bounds__(256) void vq_prep(const float* __restrict__ z,
                                               unsigned short* __restrict__ zh,
                                               unsigned short* __restrict__ zl)
{
    __shared__ float tile[64][65];
    const int tid = threadIdx.x;
    const int lane = tid & 63;
    const int sub = tid >> 6;           // 0..3
    const int b = blockIdx.x >> 6;      // 32 b
    const int t0 = (blockIdx.x & 63) * 64;
#pragma unroll
    for (int i = 0; i < 16; ++i) {
        const int d = i * 4 + sub;
        tile[lane][d] = z[((size_t)b * DD + d) * TD + t0 + lane];
    }
    __syncthreads();
#pragma unroll
    for (int i = 0; i < 16; ++i) {
        const int tl = i * 4 + sub;
        const float v = tile[tl][lane];
        const unsigned short h = f2bf(v);
        const unsigned short l = f2bf(v - bf2f(h));
        const size_t o = ((size_t)(b * TD + t0 + tl)) * DD + lane;
        zh[o] = h;
        zl[o] = l;
    }
}

// ---------------- K0b: emb -> e_hi/e_lo bf16 + fp64-exact half norms ----------------
__global__ __launch_bounds__(256) void vq_eprep(const float* __restrict__ emb,
                                                unsigned short* __restrict__ eh,
                                                unsigned short* __restrict__ el,
                                                float* __restrict__ halfnorm)
{
    const int k = blockIdx.x * 256 + threadIdx.x;
    if (k >= KK) return;
    const float* e = emb + (size_t)k * DD;
    double s = 0.0;
#pragma unroll
    for (int d = 0; d < DD; ++d) {
        const float v = e[d];
        const double dv = (double)v;
        s = fma(dv, dv, s);
        const unsigned short h = f2bf(v);
        eh[(size_t)k * DD + d] = h;
        el[(size_t)k * DD + d] = f2bf(v - bf2f(h));
    }
    halfnorm[k] = (float)(0.5 * s);
}

// ---------------- K1: MFMA screen, 32 pts/wave, B double-buffered ----------------
__global__ __launch_bounds__(256, 3) void vq_screen_mfma(
    const unsigned short* __restrict__ zh, const unsigned short* __restrict__ zl,
    const unsigned short* __restrict__ eh, const unsigned short* __restrict__ el,
    const float* __restrict__ hn,
    int* __restrict__ idx_ws, float* __restrict__ ind_out,
    int* __restrict__ nflag, int* __restrict__ flags)
{
    const int tid = threadIdx.x;
    const int lane = tid & 63;
    const int wid = tid >> 6;
    const int quad = lane >> 4;
    const int col = lane & 15;
    const int pbase = (blockIdx.x * 4 + wid) * 32;   // 32 points per wave

    // A fragments: tile0 = points pbase..+15, tile1 = +16..+31; dims quad*8..+7 / +32
    const bf16x8* pA0h = (const bf16x8*)(zh + (size_t)(pbase + col) * DD + quad * 8);
    const bf16x8* pA0l = (const bf16x8*)(zl + (size_t)(pbase + col) * DD + quad * 8);
    const bf16x8* pA1h = (const bf16x8*)(zh + (size_t)(pbase + 16 + col) * DD + quad * 8);
    const bf16x8* pA1l = (const bf16x8*)(zl + (size_t)(pbase + 16 + col) * DD + quad * 8);
    const bf16x8 A0h0 = pA0h[0], A0h1 = pA0h[4];
    const bf16x8 A0l0 = pA0l[0], A0l1 = pA0l[4];
    const bf16x8 A1h0 = pA1h[0], A1h1 = pA1h[4];
    const bf16x8 A1l0 = pA1l[0], A1l1 = pA1l[4];

    float best0[4]  = {1e30f, 1e30f, 1e30f, 1e30f};
    float best20[4] = {1e30f, 1e30f, 1e30f, 1e30f};
    int   bidx0[4]  = {0, 0, 0, 0};
    float best1[4]  = {1e30f, 1e30f, 1e30f, 1e30f};
    float best21[4] = {1e30f, 1e30f, 1e30f, 1e30f};
    int   bidx1[4]  = {0, 0, 0, 0};

    // prime B double-buffer (t = 0)
    size_t brow = (size_t)col * DD + quad * 8;
    bf16x8 Bh0 = *(const bf16x8*)(eh + brow);
    bf16x8 Bh1 = *(const bf16x8*)(eh + brow + 32);
    bf16x8 Bl0 = *(const bf16x8*)(el + brow);
    bf16x8 Bl1 = *(const bf16x8*)(el + brow + 32);
    float hnv = hn[col];

    for (int t = 0; t < KK / 16; ++t) {
        // prefetch next tile's B fragments ((t+1)&63 wraps harmlessly at the end)
        const int tn = (t + 1) & 63;
        const size_t nrow = (size_t)(tn * 16 + col) * DD + quad * 8;
        const bf16x8 nBh0 = *(const bf16x8*)(eh + nrow);
        const bf16x8 nBh1 = *(const bf16x8*)(eh + nrow + 32);
        const bf16x8 nBl0 = *(const bf16x8*)(el + nrow);
        const bf16x8 nBl1 = *(const bf16x8*)(el + nrow + 32);
        const float nhn = hn[tn * 16 + col];

        // 4 independent 3-chains (2 per point-tile)
        f32x4 p0 = {0.f, 0.f, 0.f, 0.f}, q0 = {0.f, 0.f, 0.f, 0.f};
        f32x4 p1 = {0.f, 0.f, 0.f, 0.f}, q1 = {0.f, 0.f, 0.f, 0.f};
        p0 = __builtin_amdgcn_mfma_f32_16x16x32_bf16(A0h0, Bh0, p0, 0, 0, 0);
        p1 = __builtin_amdgcn_mfma_f32_16x16x32_bf16(A1h0, Bh0, p1, 0, 0, 0);
        q0 = __builtin_amdgcn_mfma_f32_16x16x32_bf16(A0l0, Bh0, q0, 0, 0, 0);
        q1 = __builtin_amdgcn_mfma_f32_16x16x32_bf16(A1l0, Bh0, q1, 0, 0, 0);
        p0 = __builtin_amdgcn_mfma_f32_16x16x32_bf16(A0h1, Bh1, p0, 0, 0, 0);
        p1 = __builtin_amdgcn_mfma_f32_16x16x32_bf16(A1h1, Bh1, p1, 0, 0, 0);
        q0 = __builtin_amdgcn_mfma_f32_16x16x32_bf16(A0l1, Bh1, q0, 0, 0, 0);
        q1 = __builtin_amdgcn_mfma_f32_16x16x32_bf16(A1l1, Bh1, q1, 0, 0, 0);
        p0 = __builtin_amdgcn_mfma_f32_16x16x32_bf16(A0h0, Bl0, p0, 0, 0, 0);
        p1 = __builtin_amdgcn_mfma_f32_16x16x32_bf16(A1h0, Bl0, p1, 0, 0, 0);
        q0 = __builtin_amdgcn_mfma_f32_16x16x32_bf16(A0h1, Bl1, q0, 0, 0, 0);
        q1 = __builtin_amdgcn_mfma_f32_16x16x32_bf16(A1h1, Bl1, q1, 0, 0, 0);

        const int code = t * 16 + col;
#pragma unroll
        for (int r = 0; r < 4; ++r) {
            const float s0 = hnv - (p0[r] + q0[r]);
            const bool l0 = s0 < best0[r];
            best20[r] = fminf(best20[r], fmaxf(best0[r], s0));
            best0[r] = l0 ? s0 : best0[r];
            bidx0[r] = l0 ? code : bidx0[r];
            const float s1 = hnv - (p1[r] + q1[r]);
            const bool l1 = s1 < best1[r];
            best21[r] = fminf(best21[r], fmaxf(best1[r], s1));
            best1[r] = l1 ? s1 : best1[r];
            bidx1[r] = l1 ? code : bidx1[r];
        }

        Bh0 = nBh0; Bh1 = nBh1; Bl0 = nBl0; Bl1 = nBl1; hnv = nhn;
    }

    // merge across the 16 cols of each quad-group (disjoint code sets)
#pragma unroll
    for (int off = 1; off < 16; off <<= 1) {
#pragma unroll
        for (int r = 0; r < 4; ++r) {
            {
                const float ob  = __shfl_xor(best0[r],  off, 64);
                const float ob2 = __shfl_xor(best20[r], off, 64);
                const int   oi  = __shfl_xor(bidx0[r],  off, 64);
                const float nb2 = fminf(fminf(best20[r], ob2), fmaxf(best0[r], ob));
                if (ob < best0[r]) { best0[r] = ob; bidx0[r] = oi; }
                best20[r] = nb2;
            }
            {
                const float ob  = __shfl_xor(best1[r],  off, 64);
                const float ob2 = __shfl_xor(best21[r], off, 64);
                const int   oi  = __shfl_xor(bidx1[r],  off, 64);
                const float nb2 = fminf(fminf(best21[r], ob2), fmaxf(best1[r], ob));
                if (ob < best1[r]) { best1[r] = ob; bidx1[r] = oi; }
                best21[r] = nb2;
            }
        }
    }

    if (col == 0) {
#pragma unroll
        for (int r = 0; r < 4; ++r) {
            const int n0 = pbase + quad * 4 + r;
            idx_ws[n0] = bidx0[r];
            ind_out[n0] = (float)bidx0[r];
            if (best20[r] - best0[r] < MARGIN_TH) {
                const int pos = atomicAdd(nflag, 1);
                flags[pos] = n0;
            }
            const int n1 = pbase + 16 + quad * 4 + r;
            idx_ws[n1] = bidx1[r];
            ind_out[n1] = (float)bidx1[r];
            if (best21[r] - best1[r] < MARGIN_TH) {
                const int pos = atomicAdd(nflag, 1);
                flags[pos] = n1;
            }
        }
    }
}

// ---------------- K1c: fp64 exact rescan for near-tie points (wave per point) ----------------
__global__ __launch_bounds__(256) void vq_fallback(
    const float* __restrict__ z, const float* __restrict__ emb,
    int* __restrict__ idx_ws, float* __restrict__ ind_out,
    const int* __restrict__ nflag, const int* __restrict__ flags)
{
    __shared__ float zs[4][DD];
    const int total = *nflag;
    const int lane = threadIdx.x & 63;
    const int wid = threadIdx.x >> 6;
    const int gw = blockIdx.x * 4 + wid;

    for (int i = gw; i < total; i += gridDim.x * 4) {
        const int n = flags[i];
        const int b = n >> 12, t = n & 4095;
        zs[wid][lane] = z[((size_t)b * DD + lane) * TD + t];
        __builtin_amdgcn_s_waitcnt(0);
        double best = 1e300;
        int bi = KK;
        for (int kc = 0; kc < KK / 64; ++kc) {
            const int k = kc * 64 + lane;
            const float4* e = (const float4*)(emb + (size_t)k * DD);
            double dot = 0.0, nn = 0.0;
#pragma unroll
            for (int j = 0; j < 16; ++j) {
                float4 ev = e[j];
                double e0 = (double)ev.x, e1 = (double)ev.y, e2 = (double)ev.z, e3 = (double)ev.w;
                nn = fma(e0, e0, fma(e1, e1, fma(e2, e2, fma(e3, e3, nn))));
                dot = fma((double)zs[wid][4 * j + 0], e0,
                      fma((double)zs[wid][4 * j + 1], e1,
                      fma((double)zs[wid][4 * j + 2], e2,
                      fma((double)zs[wid][4 * j + 3], e3, dot))));
            }
            double s = 0.5 * nn - dot;
            if (s < best || (s == best && k < bi)) { best = s; bi = k; }
        }
        for (int off = 32; off > 0; off >>= 1) {
            double os = __shfl_down(best, off, 64);
            int oi = __shfl_down(bi, off, 64);
            if (os < best || (os == best && oi < bi)) { best = os; bi = oi; }
        }
        if (lane == 0) { idx_ws[n] = bi; ind_out[n] = (float)bi; }
    }
}

// ---------------- K2: code-range ownership scan: esum + hist, no global atomics ----------------
// 256 blocks x 4 codes each; each wave scans N/4 points with int4 coalesced idx loads.
__global__ __launch_bounds__(256) void vq_esum_scan(
    const unsigned short* __restrict__ zh, const unsigned short* __restrict__ zl,
    const int* __restrict__ idx_ws,
    float* __restrict__ esum, int* __restrict__ hist)
{
    __shared__ float acc[4][DD];
    __shared__ int scnt[4];
    const int tid = threadIdx.x;
    const int lane = tid & 63;
    const int w = tid >> 6;
    const int kbase = blockIdx.x * 4;

    acc[tid >> 6][tid & 63] = 0.f;
    if (tid < 4) scnt[tid] = 0;
    __syncthreads();

    const int4* idx4 = (const int4*)idx_ws;
    const int base4 = w * (N_PTS / 4 / 4);   // int4 units per wave = 8192

    for (int it = 0; it < 128; ++it) {
        const int i4 = base4 + it * 64 + lane;
        const int4 c = idx4[i4];
        const int bp = (base4 + it * 64) * 4;   // wave-uniform first point id

        unsigned long long m0 = __ballot((unsigned)(c.x - kbase) < 4u);
        unsigned long long m1 = __ballot((unsigned)(c.y - kbase) < 4u);
        unsigned long long m2 = __ballot((unsigned)(c.z - kbase) < 4u);
        unsigned long long m3 = __ballot((unsigned)(c.w - kbase) < 4u);

#define PROC(mj, cj, j)                                                   \
        while (mj) {                                                      \
            const int src = __ffsll(mj) - 1; mj &= mj - 1;                \
            const int pc = __shfl(cj, src, 64) - kbase;                   \
            const size_t o = (size_t)(bp + src * 4 + j) * DD + lane;      \
            const float v = bf2f(zh[o]) + bf2f(zl[o]);                    \
            atomicAdd(&acc[pc][lane], v);                                 \
            if (lane == 0) atomicAdd(&scnt[pc], 1);                       \
        }
        PROC(m0, c.x, 0)
        PROC(m1, c.y, 1)
        PROC(m2, c.z, 2)
        PROC(m3, c.w, 3)
#undef PROC
    }
    __syncthreads();

    // wave w writes its row; 4 rows exactly
    esum[(size_t)(kbase + w) * DD + lane] = acc[w][lane];
    if (tid < 4) hist[kbase + tid] = scnt[tid];
}

// ---------------- K3: EMA update + Laplace smoothing + new embedding ----------------
__global__ __launch_bounds__(1024) void vq_update(
    const float* __restrict__ cs, const int* __restrict__ hist,
    const float* __restrict__ avg, const float* __restrict__ esum,
    float* __restrict__ newE)
{
    __shared__ double red[KK];
    __shared__ float smo[KK];
    const int k = threadIdx.x;
    const double DECAY = 0.99, OMD = 1.0 - 0.99, EPSV = 1e-5;
    double ncs = DECAY * (double)cs[k] + OMD * (double)hist[k];
    red[k] = ncs;
    __syncthreads();
    for (int s = 512; s > 0; s >>= 1) {
        if (k < s) red[k] += red[k + s];
        __syncthreads();
    }
    double nsum = red[0];
    smo[k] = (float)((ncs + EPSV) / (nsum + (double)KK * EPSV) * nsum);
    __syncthreads();
    for (int it = 0; it < DD; ++it) {
        int j = it * KK + k;
        int kk = j >> 6;
        newE[j] = (float)((DECAY * (double)avg[j] + OMD * (double)esum[j]) / (double)smo[kk]);
    }
}

// ---------------- K4: gather z_q + commitment loss (finalize fused) ----------------
__global__ __launch_bounds__(256) void vq_gather_loss(
    const float* __restrict__ z, const float* __restrict__ newE,
    const int* __restrict__ idx_ws, float* __restrict__ zq_out,
    double* __restrict__ loss_acc, int* __restrict__ done_cnt,
    float* __restrict__ loss_out)
{
    const int tid = threadIdx.x;
    const int n = blockIdx.x * 256 + tid;
    const int b = n >> 12;
    const int t = n & 4095;
    const float* zb = z + ((size_t)b * DD) * TD + t;
    float* ob = zq_out + ((size_t)b * DD) * TD + t;
    const int bi = idx_ws[n];
    const float* e = newE + (size_t)bi * DD;
    double acc = 0.0;
#pragma unroll
    for (int d = 0; d < DD; ++d) {
        float q = e[d];
        float zv = zb[(size_t)d * TD];
        ob[(size_t)d * TD] = q;
        float df = zv - q;
        acc = fma((double)df, (double)df, acc);
    }
    for (int off = 32; off > 0; off >>= 1) acc += __shfl_down(acc, off, 64);
    __shared__ double wsum[4];
    const int wid = tid >> 6, lane = tid & 63;
    if (lane == 0) wsum[wid] = acc;
    __syncthreads();
    if (tid == 0) {
        atomicAdd(loss_acc, wsum[0] + wsum[1] + wsum[2] + wsum[3]);
        __threadfence();
        const int prev = atomicAdd(done_cnt, 1);
        if (prev == gridDim.x - 1) {
            __threadfence();
            *loss_out = (float)(0.25 * (*loss_acc) / (double)(N_PTS * DD));
        }
    }
}

extern "C" void kernel_launch(void* const* d_in, const int* in_sizes, int n_in,
                              void* d_out, int out_size, void* d_ws, size_t ws_size,
                              hipStream_t stream) {
    const float* z    = (const float*)d_in[0];   // [32, 64, 4096]
    const float* emb  = (const float*)d_in[1];   // [1024, 64]
    const float* cs   = (const float*)d_in[2];   // [1024]
    const float* avg  = (const float*)d_in[3];   // [1024, 64]

    float* out      = (float*)d_out;
    float* zq_out   = out;                // 8388608 floats (32 MiB)
    float* loss_out = out + 8388608;      // 1
    float* ind_out  = out + 8388609;      // 131072 (indices as float)

    // z_hi/z_lo bf16 [N][D] exactly fill the z_q region (dead before K4 rewrites it)
    unsigned short* zh = (unsigned short*)d_out;                       // 16 MiB
    unsigned short* zl = (unsigned short*)((char*)d_out + 16777216);   // 16 MiB

    char* ws = (char*)d_ws;
    int*            idx_ws   = (int*)ws;                     // 512 KB @ 0
    float*          newE     = (float*)(ws + 524288);        // 256 KB
    float*          esum     = (float*)(ws + 786432);        // 256 KB
    int*            hist     = (int*)(ws + 1048576);         // 4 KB
    int*            nflag    = (int*)(ws + 1052672);         // 4 B    [memset]
    int*            done_cnt = (int*)(ws + 1052676);         // 4 B    [memset]
    double*         loss_acc = (double*)(ws + 1052680);      // 8 B    [memset]
    float*          halfnorm = (float*)(ws + 1052688);       // 4 KB
    int*            flags    = (int*)(ws + 1064976);         // 512 KB
    unsigned short* eh       = (unsigned short*)(ws + 2113552); // 128 KB
    unsigned short* el       = (unsigned short*)(ws + 2244624); // 128 KB

    // zero nflag + done_cnt + loss_acc (contiguous 16 B)
    hipMemsetAsync(ws + 1052672, 0, 16, stream);

    vq_prep<<<2048, 256, 0, stream>>>(z, zh, zl);
    vq_eprep<<<4, 256, 0, stream>>>(emb, eh, el, halfnorm);
    vq_screen_mfma<<<1024, 256, 0, stream>>>(zh, zl, eh, el, halfnorm,
                                             idx_ws, ind_out, nflag, flags);
    vq_fallback<<<128, 256, 0, stream>>>(z, emb, idx_ws, ind_out, nflag, flags);
    vq_esum_scan<<<KK / 4, 256, 0, stream>>>(zh, zl, idx_ws, esum, hist);
    vq_update<<<1, 1024, 0, stream>>>(cs, hist, avg, esum, newE);
    vq_gather_loss<<<N_PTS / 256, 256, 0, stream>>>(z, newE, idx_ws, zq_out,
                                                    loss_acc, done_cnt, loss_out);
}

// Round 8
// 374.720 us; speedup vs baseline: 1.7520x; 1.7520x over previous
//
#include <hip/hip_runtime.h>

#define N_PTS 131072
#define TD 4096
#define DD 64
#define KK 1024
#define MARGIN_TH 2e-3f

typedef short bf16x8 __attribute__((ext_vector_type(8)));
typedef float f32x4  __attribute__((ext_vector_type(4)));

__device__ inline unsigned short f2bf(float f) {           // RNE float->bf16
    unsigned u = __float_as_uint(f);
    unsigned r = u + 0x7FFFu + ((u >> 16) & 1u);
    return (unsigned short)(r >> 16);
}
__device__ inline float bf2f(unsigned short h) {
    return __uint_as_float(((unsigned)h) << 16);
}

// ---------------- K0a: transpose z[B,D,T] -> z_hi/z_lo bf16 [N,D] ----------------
__global__ __launch_bounds__(256) void vq_prep(const float* __restrict__ z,
                                               unsigned short* __restrict__ zh,
                                               unsigned short* __restrict__ zl)
{
    __shared__ float tile[64][65];
    const int tid = threadIdx.x;
    const int lane = tid & 63;
    const int sub = tid >> 6;           // 0..3
    const int b = blockIdx.x >> 6;      // 32 b
    const int t0 = (blockIdx.x & 63) * 64;
#pragma unroll
    for (int i = 0; i < 16; ++i) {
        const int d = i * 4 + sub;
        tile[lane][d] = z[((size_t)b * DD + d) * TD + t0 + lane];
    }
    __syncthreads();
#pragma unroll
    for (int i = 0; i < 16; ++i) {
        const int tl = i * 4 + sub;
        const float v = tile[tl][lane];
        const unsigned short h = f2bf(v);
        const unsigned short l = f2bf(v - bf2f(h));
        const size_t o = ((size_t)(b * TD + t0 + tl)) * DD + lane;
        zh[o] = h;
        zl[o] = l;
    }
}

// ---------------- K0b: emb -> e_hi/e_lo bf16 + fp64-exact half norms ----------------
__global__ __launch_bounds__(256) void vq_eprep(const float* __restrict__ emb,
                                                unsigned short* __restrict__ eh,
                                                unsigned short* __restrict__ el,
                                                float* __restrict__ halfnorm)
{
    const int k = blockIdx.x * 256 + threadIdx.x;
    if (k >= KK) return;
    const float* e = emb + (size_t)k * DD;
    double s = 0.0;
#pragma unroll
    for (int d = 0; d < DD; ++d) {
        const float v = e[d];
        const double dv = (double)v;
        s = fma(dv, dv, s);
        const unsigned short h = f2bf(v);
        eh[(size_t)k * DD + d] = h;
        el[(size_t)k * DD + d] = f2bf(v - bf2f(h));
    }
    halfnorm[k] = (float)(0.5 * s);
}

// ---------------- K1: MFMA screen, 32 pts/wave, B double-buffered ----------------
__global__ __launch_bounds__(256, 3) void vq_screen_mfma(
    const unsigned short* __restrict__ zh, const unsigned short* __restrict__ zl,
    const unsigned short* __restrict__ eh, const unsigned short* __restrict__ el,
    const float* __restrict__ hn,
    int* __restrict__ idx_ws, float* __restrict__ ind_out,
    int* __restrict__ nflag, int* __restrict__ flags)
{
    const int tid = threadIdx.x;
    const int lane = tid & 63;
    const int wid = tid >> 6;
    const int quad = lane >> 4;
    const int col = lane & 15;
    const int pbase = (blockIdx.x * 4 + wid) * 32;   // 32 points per wave

    const bf16x8* pA0h = (const bf16x8*)(zh + (size_t)(pbase + col) * DD + quad * 8);
    const bf16x8* pA0l = (const bf16x8*)(zl + (size_t)(pbase + col) * DD + quad * 8);
    const bf16x8* pA1h = (const bf16x8*)(zh + (size_t)(pbase + 16 + col) * DD + quad * 8);
    const bf16x8* pA1l = (const bf16x8*)(zl + (size_t)(pbase + 16 + col) * DD + quad * 8);
    const bf16x8 A0h0 = pA0h[0], A0h1 = pA0h[4];
    const bf16x8 A0l0 = pA0l[0], A0l1 = pA0l[4];
    const bf16x8 A1h0 = pA1h[0], A1h1 = pA1h[4];
    const bf16x8 A1l0 = pA1l[0], A1l1 = pA1l[4];

    float best0[4]  = {1e30f, 1e30f, 1e30f, 1e30f};
    float best20[4] = {1e30f, 1e30f, 1e30f, 1e30f};
    int   bidx0[4]  = {0, 0, 0, 0};
    float best1[4]  = {1e30f, 1e30f, 1e30f, 1e30f};
    float best21[4] = {1e30f, 1e30f, 1e30f, 1e30f};
    int   bidx1[4]  = {0, 0, 0, 0};

    size_t brow = (size_t)col * DD + quad * 8;
    bf16x8 Bh0 = *(const bf16x8*)(eh + brow);
    bf16x8 Bh1 = *(const bf16x8*)(eh + brow + 32);
    bf16x8 Bl0 = *(const bf16x8*)(el + brow);
    bf16x8 Bl1 = *(const bf16x8*)(el + brow + 32);
    float hnv = hn[col];

    for (int t = 0; t < KK / 16; ++t) {
        const int tn = (t + 1) & 63;
        const size_t nrow = (size_t)(tn * 16 + col) * DD + quad * 8;
        const bf16x8 nBh0 = *(const bf16x8*)(eh + nrow);
        const bf16x8 nBh1 = *(const bf16x8*)(eh + nrow + 32);
        const bf16x8 nBl0 = *(const bf16x8*)(el + nrow);
        const bf16x8 nBl1 = *(const bf16x8*)(el + nrow + 32);
        const float nhn = hn[tn * 16 + col];

        f32x4 p0 = {0.f, 0.f, 0.f, 0.f}, q0 = {0.f, 0.f, 0.f, 0.f};
        f32x4 p1 = {0.f, 0.f, 0.f, 0.f}, q1 = {0.f, 0.f, 0.f, 0.f};
        p0 = __builtin_amdgcn_mfma_f32_16x16x32_bf16(A0h0, Bh0, p0, 0, 0, 0);
        p1 = __builtin_amdgcn_mfma_f32_16x16x32_bf16(A1h0, Bh0, p1, 0, 0, 0);
        q0 = __builtin_amdgcn_mfma_f32_16x16x32_bf16(A0l0, Bh0, q0, 0, 0, 0);
        q1 = __builtin_amdgcn_mfma_f32_16x16x32_bf16(A1l0, Bh0, q1, 0, 0, 0);
        p0 = __builtin_amdgcn_mfma_f32_16x16x32_bf16(A0h1, Bh1, p0, 0, 0, 0);
        p1 = __builtin_amdgcn_mfma_f32_16x16x32_bf16(A1h1, Bh1, p1, 0, 0, 0);
        q0 = __builtin_amdgcn_mfma_f32_16x16x32_bf16(A0l1, Bh1, q0, 0, 0, 0);
        q1 = __builtin_amdgcn_mfma_f32_16x16x32_bf16(A1l1, Bh1, q1, 0, 0, 0);
        p0 = __builtin_amdgcn_mfma_f32_16x16x32_bf16(A0h0, Bl0, p0, 0, 0, 0);
        p1 = __builtin_amdgcn_mfma_f32_16x16x32_bf16(A1h0, Bl0, p1, 0, 0, 0);
        q0 = __builtin_amdgcn_mfma_f32_16x16x32_bf16(A0h1, Bl1, q0, 0, 0, 0);
        q1 = __builtin_amdgcn_mfma_f32_16x16x32_bf16(A1h1, Bl1, q1, 0, 0, 0);

        const int code = t * 16 + col;
#pragma unroll
        for (int r = 0; r < 4; ++r) {
            const float s0 = hnv - (p0[r] + q0[r]);
            const bool l0 = s0 < best0[r];
            best20[r] = fminf(best20[r], fmaxf(best0[r], s0));
            best0[r] = l0 ? s0 : best0[r];
            bidx0[r] = l0 ? code : bidx0[r];
            const float s1 = hnv - (p1[r] + q1[r]);
            const bool l1 = s1 < best1[r];
            best21[r] = fminf(best21[r], fmaxf(best1[r], s1));
            best1[r] = l1 ? s1 : best1[r];
            bidx1[r] = l1 ? code : bidx1[r];
        }

        Bh0 = nBh0; Bh1 = nBh1; Bl0 = nBl0; Bl1 = nBl1; hnv = nhn;
    }

#pragma unroll
    for (int off = 1; off < 16; off <<= 1) {
#pragma unroll
        for (int r = 0; r < 4; ++r) {
            {
                const float ob  = __shfl_xor(best0[r],  off, 64);
                const float ob2 = __shfl_xor(best20[r], off, 64);
                const int   oi  = __shfl_xor(bidx0[r],  off, 64);
                const float nb2 = fminf(fminf(best20[r], ob2), fmaxf(best0[r], ob));
                if (ob < best0[r]) { best0[r] = ob; bidx0[r] = oi; }
                best20[r] = nb2;
            }
            {
                const float ob  = __shfl_xor(best1[r],  off, 64);
                const float ob2 = __shfl_xor(best21[r], off, 64);
                const int   oi  = __shfl_xor(bidx1[r],  off, 64);
                const float nb2 = fminf(fminf(best21[r], ob2), fmaxf(best1[r], ob));
                if (ob < best1[r]) { best1[r] = ob; bidx1[r] = oi; }
                best21[r] = nb2;
            }
        }
    }

    if (col == 0) {
#pragma unroll
        for (int r = 0; r < 4; ++r) {
            const int n0 = pbase + quad * 4 + r;
            idx_ws[n0] = bidx0[r];
            ind_out[n0] = (float)bidx0[r];
            if (best20[r] - best0[r] < MARGIN_TH) {
                const int pos = atomicAdd(nflag, 1);
                flags[pos] = n0;
            }
            const int n1 = pbase + 16 + quad * 4 + r;
            idx_ws[n1] = bidx1[r];
            ind_out[n1] = (float)bidx1[r];
            if (best21[r] - best1[r] < MARGIN_TH) {
                const int pos = atomicAdd(nflag, 1);
                flags[pos] = n1;
            }
        }
    }
}

// ---------------- K1c: fp64 exact rescan for near-tie points (wave per point) ----------------
__global__ __launch_bounds__(256) void vq_fallback(
    const float* __restrict__ z, const float* __restrict__ emb,
    int* __restrict__ idx_ws, float* __restrict__ ind_out,
    const int* __restrict__ nflag, const int* __restrict__ flags)
{
    __shared__ float zs[4][DD];
    const int total = *nflag;
    const int lane = threadIdx.x & 63;
    const int wid = threadIdx.x >> 6;
    const int gw = blockIdx.x * 4 + wid;

    for (int i = gw; i < total; i += gridDim.x * 4) {
        const int n = flags[i];
        const int b = n >> 12, t = n & 4095;
        zs[wid][lane] = z[((size_t)b * DD + lane) * TD + t];
        __builtin_amdgcn_s_waitcnt(0);
        double best = 1e300;
        int bi = KK;
        for (int kc = 0; kc < KK / 64; ++kc) {
            const int k = kc * 64 + lane;
            const float4* e = (const float4*)(emb + (size_t)k * DD);
            double dot = 0.0, nn = 0.0;
#pragma unroll
            for (int j = 0; j < 16; ++j) {
                float4 ev = e[j];
                double e0 = (double)ev.x, e1 = (double)ev.y, e2 = (double)ev.z, e3 = (double)ev.w;
                nn = fma(e0, e0, fma(e1, e1, fma(e2, e2, fma(e3, e3, nn))));
                dot = fma((double)zs[wid][4 * j + 0], e0,
                      fma((double)zs[wid][4 * j + 1], e1,
                      fma((double)zs[wid][4 * j + 2], e2,
                      fma((double)zs[wid][4 * j + 3], e3, dot))));
            }
            double s = 0.5 * nn - dot;
            if (s < best || (s == best && k < bi)) { best = s; bi = k; }
        }
        for (int off = 32; off > 0; off >>= 1) {
            double os = __shfl_down(best, off, 64);
            int oi = __shfl_down(bi, off, 64);
            if (os < best || (os == best && oi < bi)) { best = os; bi = oi; }
        }
        if (lane == 0) { idx_ws[n] = bi; ind_out[n] = (float)bi; }
    }
}

// ---------------- K2a: histogram of final indices (LDS-privatized) ----------------
__global__ __launch_bounds__(256) void vq_hist(const int* __restrict__ idx_ws, int* __restrict__ hist)
{
    __shared__ int h[KK];
    for (int i = threadIdx.x; i < KK; i += 256) h[i] = 0;
    __syncthreads();
    const int base = blockIdx.x * 2048;
#pragma unroll
    for (int j = 0; j < 8; ++j)
        atomicAdd(&h[idx_ws[base + j * 256 + threadIdx.x]], 1);
    __syncthreads();
    for (int i = threadIdx.x; i < KK; i += 256)
        if (h[i]) atomicAdd(&hist[i], h[i]);
}

// ---------------- K2b: exclusive scan -> cursor ----------------
__global__ __launch_bounds__(1024) void vq_prefix(const int* __restrict__ hist,
                                                  int* __restrict__ cursor)
{
    __shared__ int tmp[KK];
    const int k = threadIdx.x;
    const int c = hist[k];
    tmp[k] = c;
    __syncthreads();
    for (int off = 1; off < KK; off <<= 1) {
        int u = (k >= off) ? tmp[k - off] : 0;
        __syncthreads();
        tmp[k] += u;
        __syncthreads();
    }
    cursor[k] = tmp[k] - c;  // exclusive
}

// ---------------- K2c: scatter point ids into per-code lists ----------------
__global__ __launch_bounds__(256) void vq_scatter(const int* __restrict__ idx_ws,
                                                  int* __restrict__ cursor, int* __restrict__ order)
{
    const int n = blockIdx.x * 256 + threadIdx.x;
    const int bi = idx_ws[n];
    const int pos = atomicAdd(&cursor[bi], 1);
    order[pos] = n;
}

// ---------------- K2d: balanced segment sum: 64 sorted positions per wave ----------------
// All row addresses known up front -> fully pipelined gathers; flush at run
// boundaries (wave-uniform) with spread fp32 atomics (~1.5 per wave).
__global__ __launch_bounds__(256) void vq_esum2(
    const unsigned short* __restrict__ zh, const unsigned short* __restrict__ zl,
    const int* __restrict__ idx_ws, const int* __restrict__ order,
    float* __restrict__ esum)
{
    const int tid = threadIdx.x;
    const int lane = tid & 63;
    const int w = tid >> 6;
    const int base = blockIdx.x * 256 + w * 64;   // this wave's 64 sorted positions

    const int pid_l = order[base + lane];          // coalesced
    const int code_l = idx_ws[pid_l];              // gather (one per lane)

    float v[64];
#pragma unroll
    for (int j = 0; j < 64; ++j) {
        const int pj = __shfl(pid_l, j, 64);
        const size_t o = (size_t)pj * DD + lane;   // 128 B coalesced per row
        v[j] = bf2f(zh[o]) + bf2f(zl[o]);
    }

    float racc = 0.f;
    int cur = __shfl(code_l, 0, 64);
#pragma unroll
    for (int j = 0; j < 64; ++j) {
        const int cj = __shfl(code_l, j, 64);      // wave-uniform
        if (cj != cur) {
            atomicAdd(&esum[(size_t)cur * DD + lane], racc);
            racc = 0.f;
            cur = cj;
        }
        racc += v[j];
    }
    atomicAdd(&esum[(size_t)cur * DD + lane], racc);
}

// ---------------- K3: EMA update + Laplace smoothing + new embedding ----------------
__global__ __launch_bounds__(1024) void vq_update(
    const float* __restrict__ cs, const int* __restrict__ hist,
    const float* __restrict__ avg, const float* __restrict__ esum,
    float* __restrict__ newE)
{
    __shared__ double red[KK];
    __shared__ float smo[KK];
    const int k = threadIdx.x;
    const double DECAY = 0.99, OMD = 1.0 - 0.99, EPSV = 1e-5;
    double ncs = DECAY * (double)cs[k] + OMD * (double)hist[k];
    red[k] = ncs;
    __syncthreads();
    for (int s = 512; s > 0; s >>= 1) {
        if (k < s) red[k] += red[k + s];
        __syncthreads();
    }
    double nsum = red[0];
    smo[k] = (float)((ncs + EPSV) / (nsum + (double)KK * EPSV) * nsum);
    __syncthreads();
    for (int it = 0; it < DD; ++it) {
        int j = it * KK + k;
        int kk = j >> 6;
        newE[j] = (float)((DECAY * (double)avg[j] + OMD * (double)esum[j]) / (double)smo[kk]);
    }
}

// ---------------- K4: gather z_q + commitment loss (finalize fused) ----------------
__global__ __launch_bounds__(256) void vq_gather_loss(
    const float* __restrict__ z, const float* __restrict__ newE,
    const int* __restrict__ idx_ws, float* __restrict__ zq_out,
    double* __restrict__ loss_acc, int* __restrict__ done_cnt,
    float* __restrict__ loss_out)
{
    const int tid = threadIdx.x;
    const int n = blockIdx.x * 256 + tid;
    const int b = n >> 12;
    const int t = n & 4095;
    const float* zb = z + ((size_t)b * DD) * TD + t;
    float* ob = zq_out + ((size_t)b * DD) * TD + t;
    const int bi = idx_ws[n];
    const float* e = newE + (size_t)bi * DD;
    double acc = 0.0;
#pragma unroll
    for (int d = 0; d < DD; ++d) {
        float q = e[d];
        float zv = zb[(size_t)d * TD];
        ob[(size_t)d * TD] = q;
        float df = zv - q;
        acc = fma((double)df, (double)df, acc);
    }
    for (int off = 32; off > 0; off >>= 1) acc += __shfl_down(acc, off, 64);
    __shared__ double wsum[4];
    const int wid = tid >> 6, lane = tid & 63;
    if (lane == 0) wsum[wid] = acc;
    __syncthreads();
    if (tid == 0) {
        atomicAdd(loss_acc, wsum[0] + wsum[1] + wsum[2] + wsum[3]);
        __threadfence();
        const int prev = atomicAdd(done_cnt, 1);
        if (prev == gridDim.x - 1) {
            __threadfence();
            *loss_out = (float)(0.25 * (*loss_acc) / (double)(N_PTS * DD));
        }
    }
}

extern "C" void kernel_launch(void* const* d_in, const int* in_sizes, int n_in,
                              void* d_out, int out_size, void* d_ws, size_t ws_size,
                              hipStream_t stream) {
    const float* z    = (const float*)d_in[0];   // [32, 64, 4096]
    const float* emb  = (const float*)d_in[1];   // [1024, 64]
    const float* cs   = (const float*)d_in[2];   // [1024]
    const float* avg  = (const float*)d_in[3];   // [1024, 64]

    float* out      = (float*)d_out;
    float* zq_out   = out;                // 8388608 floats (32 MiB)
    float* loss_out = out + 8388608;      // 1
    float* ind_out  = out + 8388609;      // 131072 (indices as float)

    // z_hi/z_lo bf16 [N][D] exactly fill the z_q region (dead before K4 rewrites it)
    unsigned short* zh = (unsigned short*)d_out;                       // 16 MiB
    unsigned short* zl = (unsigned short*)((char*)d_out + 16777216);   // 16 MiB

    char* ws = (char*)d_ws;
    int*            idx_ws   = (int*)ws;                     // 512 KB @ 0
    float*          newE     = (float*)(ws + 524288);        // 256 KB
    float*          esum     = (float*)(ws + 786432);        // 256 KB [memset]
    int*            hist     = (int*)(ws + 1048576);         // 4 KB   [memset]
    int*            nflag    = (int*)(ws + 1052672);         // 4 B    [memset]
    int*            done_cnt = (int*)(ws + 1052676);         // 4 B    [memset]
    double*         loss_acc = (double*)(ws + 1052680);      // 8 B    [memset]
    float*          halfnorm = (float*)(ws + 1052688);       // 4 KB
    int*            cursor   = (int*)(ws + 1056784);         // 4 KB
    int*            flags    = (int*)(ws + 1060880);         // 512 KB
    int*            order    = (int*)(ws + 1585168);         // 512 KB
    unsigned short* eh       = (unsigned short*)(ws + 2109456); // 128 KB
    unsigned short* el       = (unsigned short*)(ws + 2240528); // 128 KB (end ~2.37 MB)

    // zero esum + hist + nflag + done_cnt + loss_acc (contiguous 786432..1052688)
    hipMemsetAsync(ws + 786432, 0, 266256, stream);

    vq_prep<<<2048, 256, 0, stream>>>(z, zh, zl);
    vq_eprep<<<4, 256, 0, stream>>>(emb, eh, el, halfnorm);
    vq_screen_mfma<<<1024, 256, 0, stream>>>(zh, zl, eh, el, halfnorm,
                                             idx_ws, ind_out, nflag, flags);
    vq_fallback<<<128, 256, 0, stream>>>(z, emb, idx_ws, ind_out, nflag, flags);
    vq_hist<<<64, 256, 0, stream>>>(idx_ws, hist);
    vq_prefix<<<1, 1024, 0, stream>>>(hist, cursor);
    vq_scatter<<<N_PTS / 256, 256, 0, stream>>>(idx_ws, cursor, order);
    vq_esum2<<<N_PTS / 256, 256, 0, stream>>>(zh, zl, idx_ws, order, esum);
    vq_update<<<1, 1024, 0, stream>>>(cs, hist, avg, esum, newE);
    vq_gather_loss<<<N_PTS / 256, 256, 0, stream>>>(z, newE, idx_ws, zq_out,
                                                    loss_acc, done_cnt, loss_out);
}

// Round 9
// 303.076 us; speedup vs baseline: 2.1662x; 1.2364x over previous
//
#include <hip/hip_runtime.h>

#define N_PTS 131072
#define TD 4096
#define DD 64
#define KK 1024
#define MARGIN_TH 2e-3f
#define BPAD 72   // ushorts per code row in LDS (64 + 8 pad = 144 B = 36 dwords)

typedef short bf16x8 __attribute__((ext_vector_type(8)));
typedef float f32x4  __attribute__((ext_vector_type(4)));

__device__ inline unsigned short f2bf(float f) {           // RNE float->bf16
    unsigned u = __float_as_uint(f);
    unsigned r = u + 0x7FFFu + ((u >> 16) & 1u);
    return (unsigned short)(r >> 16);
}
__device__ inline float bf2f(unsigned short h) {
    return __uint_as_float(((unsigned)h) << 16);
}

// ---------------- K0a: transpose z[B,D,T] -> z_hi/z_lo bf16 [N,D], wide I/O ----------------
__global__ __launch_bounds__(256) void vq_prep(const float* __restrict__ z,
                                               unsigned short* __restrict__ zh,
                                               unsigned short* __restrict__ zl)
{
    __shared__ float tile[64][65];
    const int tid = threadIdx.x;
    const int b = blockIdx.x >> 6;
    const int t0 = (blockIdx.x & 63) * 64;

    // phase 1: thread (d = tid>>2, tq = tid&3) loads 4 float4 along t
    const int d = tid >> 2, tq = tid & 3;
#pragma unroll
    for (int it = 0; it < 4; ++it) {
        const int tt = tq * 16 + it * 4;
        const float4 v = *(const float4*)(z + ((size_t)b * DD + d) * TD + t0 + tt);
        tile[d][tt] = v.x; tile[d][tt + 1] = v.y; tile[d][tt + 2] = v.z; tile[d][tt + 3] = v.w;
    }
    __syncthreads();

    // phase 2: thread (p = tid>>2, dg = tid&3) emits 16 dims of point t0+p (32 B hi + 32 B lo)
    const int p = tid >> 2, dg = tid & 3;
    bf16x8 h0, h1, l0, l1;
#pragma unroll
    for (int j = 0; j < 8; ++j) {
        const float v0 = tile[dg * 16 + j][p];
        const unsigned short a = f2bf(v0);
        h0[j] = (short)a; l0[j] = (short)f2bf(v0 - bf2f(a));
        const float v1 = tile[dg * 16 + 8 + j][p];
        const unsigned short c = f2bf(v1);
        h1[j] = (short)c; l1[j] = (short)f2bf(v1 - bf2f(c));
    }
    const size_t o = ((size_t)(b * TD + t0 + p)) * DD + dg * 16;
    *(bf16x8*)(zh + o) = h0;
    *(bf16x8*)(zh + o + 8) = h1;
    *(bf16x8*)(zl + o) = l0;
    *(bf16x8*)(zl + o + 8) = l1;
}

// ---------------- K0b: emb -> e_hi/e_lo bf16 + fp64-exact half norms ----------------
__global__ __launch_bounds__(256) void vq_eprep(const float* __restrict__ emb,
                                                unsigned short* __restrict__ eh,
                                                unsigned short* __restrict__ el,
                                                float* __restrict__ halfnorm)
{
    const int k = blockIdx.x * 256 + threadIdx.x;
    if (k >= KK) return;
    const float* e = emb + (size_t)k * DD;
    double s = 0.0;
#pragma unroll
    for (int d = 0; d < DD; ++d) {
        const float v = e[d];
        const double dv = (double)v;
        s = fma(dv, dv, s);
        const unsigned short h = f2bf(v);
        eh[(size_t)k * DD + d] = h;
        el[(size_t)k * DD + d] = f2bf(v - bf2f(h));
    }
    halfnorm[k] = (float)(0.5 * s);
}

// ---------------- K1: MFMA screen, 32 pts/wave, B staged in LDS (double-buffered) ----------------
__global__ __launch_bounds__(256, 4) void vq_screen_mfma(
    const unsigned short* __restrict__ zh, const unsigned short* __restrict__ zl,
    const unsigned short* __restrict__ eh, const unsigned short* __restrict__ el,
    const float* __restrict__ hn,
    int* __restrict__ idx_ws, float* __restrict__ ind_out,
    int* __restrict__ nflag, int* __restrict__ flags)
{
    __shared__ __align__(16) unsigned short ehs[2][16 * BPAD];
    __shared__ __align__(16) unsigned short els[2][16 * BPAD];
    __shared__ float hns[2][16];

    const int tid = threadIdx.x;
    const int lane = tid & 63;
    const int wid = tid >> 6;
    const int quad = lane >> 4;
    const int col = lane & 15;
    const int pbase = blockIdx.x * 128 + wid * 32;   // 32 points per wave

    // A fragments
    const bf16x8* pA0h = (const bf16x8*)(zh + (size_t)(pbase + col) * DD + quad * 8);
    const bf16x8* pA0l = (const bf16x8*)(zl + (size_t)(pbase + col) * DD + quad * 8);
    const bf16x8* pA1h = (const bf16x8*)(zh + (size_t)(pbase + 16 + col) * DD + quad * 8);
    const bf16x8* pA1l = (const bf16x8*)(zl + (size_t)(pbase + 16 + col) * DD + quad * 8);
    const bf16x8 A0h0 = pA0h[0], A0h1 = pA0h[4];
    const bf16x8 A0l0 = pA0l[0], A0l1 = pA0l[4];
    const bf16x8 A1h0 = pA1h[0], A1h1 = pA1h[4];
    const bf16x8 A1l0 = pA1l[0], A1l1 = pA1l[4];

    // staging role: threads 0..127 stage eh, 128..255 stage el (wave-uniform)
    const int sidx = tid & 127;
    const int scode = sidx >> 3;              // 0..15
    const int schunk = sidx & 7;              // 0..7 (8 ushorts)
    const bool shi = (tid < 128);
    const unsigned short* sgl = shi ? eh : el;
    const int soff = scode * BPAD + schunk * 8;

    // preload tile 0
    {
        const bf16x8 r = *(const bf16x8*)(sgl + (size_t)scode * DD + schunk * 8);
        *(bf16x8*)((shi ? &ehs[0][0] : &els[0][0]) + soff) = r;
        if (tid < 16) hns[0][tid] = hn[tid];
    }
    __syncthreads();

    float best0[4]  = {1e30f, 1e30f, 1e30f, 1e30f};
    float best20[4] = {1e30f, 1e30f, 1e30f, 1e30f};
    int   bidx0[4]  = {0, 0, 0, 0};
    float best1[4]  = {1e30f, 1e30f, 1e30f, 1e30f};
    float best21[4] = {1e30f, 1e30f, 1e30f, 1e30f};
    int   bidx1[4]  = {0, 0, 0, 0};

    for (int t = 0; t < KK / 16; ++t) {
        const int cur = t & 1;

        // issue next tile's global loads (no wait yet)
        bf16x8 nr;
        float nh = 0.f;
        if (t < 63) {
            nr = *(const bf16x8*)(sgl + (size_t)((t + 1) * 16 + scode) * DD + schunk * 8);
            if (tid < 16) nh = hn[(t + 1) * 16 + tid];
        }

        // B fragments from LDS (pad-144: even 8-phase, no extra conflicts)
        const unsigned short* bh = &ehs[cur][col * BPAD + quad * 8];
        const unsigned short* bl = &els[cur][col * BPAD + quad * 8];
        const bf16x8 Bh0 = *(const bf16x8*)(bh);
        const bf16x8 Bh1 = *(const bf16x8*)(bh + 32);
        const bf16x8 Bl0 = *(const bf16x8*)(bl);
        const bf16x8 Bl1 = *(const bf16x8*)(bl + 32);
        const float hnv = hns[cur][col];

        // write next tile into the other buffer
        if (t < 63) {
            *(bf16x8*)((shi ? &ehs[cur ^ 1][0] : &els[cur ^ 1][0]) + soff) = nr;
            if (tid < 16) hns[cur ^ 1][tid] = nh;
        }

        // 4 independent 3-chains (2 per point-tile)
        f32x4 p0 = {0.f, 0.f, 0.f, 0.f}, q0 = {0.f, 0.f, 0.f, 0.f};
        f32x4 p1 = {0.f, 0.f, 0.f, 0.f}, q1 = {0.f, 0.f, 0.f, 0.f};
        p0 = __builtin_amdgcn_mfma_f32_16x16x32_bf16(A0h0, Bh0, p0, 0, 0, 0);
        p1 = __builtin_amdgcn_mfma_f32_16x16x32_bf16(A1h0, Bh0, p1, 0, 0, 0);
        q0 = __builtin_amdgcn_mfma_f32_16x16x32_bf16(A0l0, Bh0, q0, 0, 0, 0);
        q1 = __builtin_amdgcn_mfma_f32_16x16x32_bf16(A1l0, Bh0, q1, 0, 0, 0);
        p0 = __builtin_amdgcn_mfma_f32_16x16x32_bf16(A0h1, Bh1, p0, 0, 0, 0);
        p1 = __builtin_amdgcn_mfma_f32_16x16x32_bf16(A1h1, Bh1, p1, 0, 0, 0);
        q0 = __builtin_amdgcn_mfma_f32_16x16x32_bf16(A0l1, Bh1, q0, 0, 0, 0);
        q1 = __builtin_amdgcn_mfma_f32_16x16x32_bf16(A1l1, Bh1, q1, 0, 0, 0);
        p0 = __builtin_amdgcn_mfma_f32_16x16x32_bf16(A0h0, Bl0, p0, 0, 0, 0);
        p1 = __builtin_amdgcn_mfma_f32_16x16x32_bf16(A1h0, Bl0, p1, 0, 0, 0);
        q0 = __builtin_amdgcn_mfma_f32_16x16x32_bf16(A0h1, Bl1, q0, 0, 0, 0);
        q1 = __builtin_amdgcn_mfma_f32_16x16x32_bf16(A1h1, Bl1, q1, 0, 0, 0);

        const int code = t * 16 + col;
#pragma unroll
        for (int r = 0; r < 4; ++r) {
            const float s0 = hnv - (p0[r] + q0[r]);
            const bool l0 = s0 < best0[r];
            best20[r] = fminf(best20[r], fmaxf(best0[r], s0));
            best0[r] = l0 ? s0 : best0[r];
            bidx0[r] = l0 ? code : bidx0[r];
            const float s1 = hnv - (p1[r] + q1[r]);
            const bool l1 = s1 < best1[r];
            best21[r] = fminf(best21[r], fmaxf(best1[r], s1));
            best1[r] = l1 ? s1 : best1[r];
            bidx1[r] = l1 ? code : bidx1[r];
        }

        __syncthreads();
    }

    // merge across the 16 cols of each quad-group (disjoint code sets)
#pragma unroll
    for (int off = 1; off < 16; off <<= 1) {
#pragma unroll
        for (int r = 0; r < 4; ++r) {
            {
                const float ob  = __shfl_xor(best0[r],  off, 64);
                const float ob2 = __shfl_xor(best20[r], off, 64);
                const int   oi  = __shfl_xor(bidx0[r],  off, 64);
                const float nb2 = fminf(fminf(best20[r], ob2), fmaxf(best0[r], ob));
                if (ob < best0[r]) { best0[r] = ob; bidx0[r] = oi; }
                best20[r] = nb2;
            }
            {
                const float ob  = __shfl_xor(best1[r],  off, 64);
                const float ob2 = __shfl_xor(best21[r], off, 64);
                const int   oi  = __shfl_xor(bidx1[r],  off, 64);
                const float nb2 = fminf(fminf(best21[r], ob2), fmaxf(best1[r], ob));
                if (ob < best1[r]) { best1[r] = ob; bidx1[r] = oi; }
                best21[r] = nb2;
            }
        }
    }

    if (col == 0) {
#pragma unroll
        for (int r = 0; r < 4; ++r) {
            const int n0 = pbase + quad * 4 + r;
            idx_ws[n0] = bidx0[r];
            ind_out[n0] = (float)bidx0[r];
            if (best20[r] - best0[r] < MARGIN_TH) {
                const int pos = atomicAdd(nflag, 1);
                flags[pos] = n0;
            }
            const int n1 = pbase + 16 + quad * 4 + r;
            idx_ws[n1] = bidx1[r];
            ind_out[n1] = (float)bidx1[r];
            if (best21[r] - best1[r] < MARGIN_TH) {
                const int pos = atomicAdd(nflag, 1);
                flags[pos] = n1;
            }
        }
    }
}

// ---------------- K1c: fp64 exact rescan for near-tie points (wave per point) ----------------
__global__ __launch_bounds__(256) void vq_fallback(
    const float* __restrict__ z, const float* __restrict__ emb,
    int* __restrict__ idx_ws, float* __restrict__ ind_out,
    const int* __restrict__ nflag, const int* __restrict__ flags)
{
    __shared__ float zs[4][DD];
    const int total = *nflag;
    const int lane = threadIdx.x & 63;
    const int wid = threadIdx.x >> 6;
    const int gw = blockIdx.x * 4 + wid;

    for (int i = gw; i < total; i += gridDim.x * 4) {
        const int n = flags[i];
        const int b = n >> 12, t = n & 4095;
        zs[wid][lane] = z[((size_t)b * DD + lane) * TD + t];
        __builtin_amdgcn_s_waitcnt(0);
        double best = 1e300;
        int bi = KK;
        for (int kc = 0; kc < KK / 64; ++kc) {
            const int k = kc * 64 + lane;
            const float4* e = (const float4*)(emb + (size_t)k * DD);
            double dot = 0.0, nn = 0.0;
#pragma unroll
            for (int j = 0; j < 16; ++j) {
                float4 ev = e[j];
                double e0 = (double)ev.x, e1 = (double)ev.y, e2 = (double)ev.z, e3 = (double)ev.w;
                nn = fma(e0, e0, fma(e1, e1, fma(e2, e2, fma(e3, e3, nn))));
                dot = fma((double)zs[wid][4 * j + 0], e0,
                      fma((double)zs[wid][4 * j + 1], e1,
                      fma((double)zs[wid][4 * j + 2], e2,
                      fma((double)zs[wid][4 * j + 3], e3, dot))));
            }
            double s = 0.5 * nn - dot;
            if (s < best || (s == best && k < bi)) { best = s; bi = k; }
        }
        for (int off = 32; off > 0; off >>= 1) {
            double os = __shfl_down(best, off, 64);
            int oi = __shfl_down(bi, off, 64);
            if (os < best || (os == best && oi < bi)) { best = os; bi = oi; }
        }
        if (lane == 0) { idx_ws[n] = bi; ind_out[n] = (float)bi; }
    }
}

// ---------------- K2a: histogram of final indices (LDS-privatized) ----------------
__global__ __launch_bounds__(256) void vq_hist(const int* __restrict__ idx_ws, int* __restrict__ hist)
{
    __shared__ int h[KK];
    for (int i = threadIdx.x; i < KK; i += 256) h[i] = 0;
    __syncthreads();
    const int base = blockIdx.x * 2048;
#pragma unroll
    for (int j = 0; j < 8; ++j)
        atomicAdd(&h[idx_ws[base + j * 256 + threadIdx.x]], 1);
    __syncthreads();
    for (int i = threadIdx.x; i < KK; i += 256)
        if (h[i]) atomicAdd(&hist[i], h[i]);
}

// ---------------- K2b: exclusive scan -> cursor, plus Laplace smoothing -> rsmo ----------------
__global__ __launch_bounds__(1024) void vq_prefix_smo(
    const int* __restrict__ hist, const float* __restrict__ cs,
    int* __restrict__ cursor, float* __restrict__ rsmo)
{
    __shared__ int tmp[KK];
    __shared__ double dred[KK];
    const int k = threadIdx.x;
    const int c = hist[k];
    tmp[k] = c;
    const double ncs = 0.99 * (double)cs[k] + 0.01 * (double)c;
    dred[k] = ncs;
    __syncthreads();
    for (int off = 1; off < KK; off <<= 1) {
        int u = (k >= off) ? tmp[k - off] : 0;
        __syncthreads();
        tmp[k] += u;
        __syncthreads();
    }
    cursor[k] = tmp[k] - c;  // exclusive
    for (int s = 512; s > 0; s >>= 1) {
        if (k < s) dred[k] += dred[k + s];
        __syncthreads();
    }
    const double nsum = dred[0];
    const double smo = (ncs + 1e-5) / (nsum + (double)KK * 1e-5) * nsum;
    rsmo[k] = (float)(1.0 / smo);
}

// ---------------- K2c: scatter point ids into per-code lists ----------------
__global__ __launch_bounds__(256) void vq_scatter(const int* __restrict__ idx_ws,
                                                  int* __restrict__ cursor, int* __restrict__ order)
{
    const int n = blockIdx.x * 256 + threadIdx.x;
    const int bi = idx_ws[n];
    const int pos = atomicAdd(&cursor[bi], 1);
    order[pos] = n;
}

// ---------------- K2d: balanced segment sum: 64 sorted positions per wave ----------------
__global__ __launch_bounds__(256) void vq_esum2(
    const unsigned short* __restrict__ zh, const unsigned short* __restrict__ zl,
    const int* __restrict__ idx_ws, const int* __restrict__ order,
    float* __restrict__ esum)
{
    const int tid = threadIdx.x;
    const int lane = tid & 63;
    const int w = tid >> 6;
    const int base = blockIdx.x * 256 + w * 64;   // this wave's 64 sorted positions

    const int pid_l = order[base + lane];          // coalesced
    const int code_l = idx_ws[pid_l];              // gather (one per lane)

    float v[64];
#pragma unroll
    for (int j = 0; j < 64; ++j) {
        const int pj = __shfl(pid_l, j, 64);
        const size_t o = (size_t)pj * DD + lane;   // 128 B coalesced per row
        v[j] = bf2f(zh[o]) + bf2f(zl[o]);
    }

    float racc = 0.f;
    int cur = __shfl(code_l, 0, 64);
#pragma unroll
    for (int j = 0; j < 64; ++j) {
        const int cj = __shfl(code_l, j, 64);      // wave-uniform
        if (cj != cur) {
            atomicAdd(&esum[(size_t)cur * DD + lane], racc);
            racc = 0.f;
            cur = cj;
        }
        racc += v[j];
    }
    atomicAdd(&esum[(size_t)cur * DD + lane], racc);
}

// ---------------- K3: new embedding (parallel) ----------------
__global__ __launch_bounds__(256) void vq_newE(
    const float* __restrict__ avg, const float* __restrict__ esum,
    const float* __restrict__ rsmo, float* __restrict__ newE)
{
    const int j = blockIdx.x * 256 + threadIdx.x;   // 65536 total
    newE[j] = (float)((0.99 * (double)avg[j] + 0.01 * (double)esum[j]) * (double)rsmo[j >> 6]);
}

// ---------------- K4: gather z_q + commitment loss (finalize fused) ----------------
__global__ __launch_bounds__(256) void vq_gather_loss(
    const float* __restrict__ z, const float* __restrict__ newE,
    const int* __restrict__ idx_ws, float* __restrict__ zq_out,
    double* __restrict__ loss_acc, int* __restrict__ done_cnt,
    float* __restrict__ loss_out)
{
    const int tid = threadIdx.x;
    const int n = blockIdx.x * 256 + tid;
    const int b = n >> 12;
    const int t = n & 4095;
    const float* zb = z + ((size_t)b * DD) * TD + t;
    float* ob = zq_out + ((size_t)b * DD) * TD + t;
    const int bi = idx_ws[n];
    const float* e = newE + (size_t)bi * DD;
    double acc = 0.0;
#pragma unroll
    for (int d = 0; d < DD; ++d) {
        float q = e[d];
        float zv = zb[(size_t)d * TD];
        ob[(size_t)d * TD] = q;
        float df = zv - q;
        acc = fma((double)df, (double)df, acc);
    }
    for (int off = 32; off > 0; off >>= 1) acc += __shfl_down(acc, off, 64);
    __shared__ double wsum[4];
    const int wid = tid >> 6, lane = tid & 63;
    if (lane == 0) wsum[wid] = acc;
    __syncthreads();
    if (tid == 0) {
        atomicAdd(loss_acc, wsum[0] + wsum[1] + wsum[2] + wsum[3]);
        __threadfence();
        const int prev = atomicAdd(done_cnt, 1);
        if (prev == gridDim.x - 1) {
            __threadfence();
            *loss_out = (float)(0.25 * (*loss_acc) / (double)(N_PTS * DD));
        }
    }
}

extern "C" void kernel_launch(void* const* d_in, const int* in_sizes, int n_in,
                              void* d_out, int out_size, void* d_ws, size_t ws_size,
                              hipStream_t stream) {
    const float* z    = (const float*)d_in[0];   // [32, 64, 4096]
    const float* emb  = (const float*)d_in[1];   // [1024, 64]
    const float* cs   = (const float*)d_in[2];   // [1024]
    const float* avg  = (const float*)d_in[3];   // [1024, 64]

    float* out      = (float*)d_out;
    float* zq_out   = out;                // 8388608 floats (32 MiB)
    float* loss_out = out + 8388608;      // 1
    float* ind_out  = out + 8388609;      // 131072 (indices as float)

    // z_hi/z_lo bf16 [N][D] exactly fill the z_q region (dead before K4 rewrites it)
    unsigned short* zh = (unsigned short*)d_out;                       // 16 MiB
    unsigned short* zl = (unsigned short*)((char*)d_out + 16777216);   // 16 MiB

    char* ws = (char*)d_ws;
    int*            idx_ws   = (int*)ws;                     // 512 KB @ 0
    float*          newE     = (float*)(ws + 524288);        // 256 KB
    float*          esum     = (float*)(ws + 786432);        // 256 KB [memset]
    int*            hist     = (int*)(ws + 1048576);         // 4 KB   [memset]
    int*            nflag    = (int*)(ws + 1052672);         // 4 B    [memset]
    int*            done_cnt = (int*)(ws + 1052676);         // 4 B    [memset]
    double*         loss_acc = (double*)(ws + 1052680);      // 8 B    [memset]
    float*          halfnorm = (float*)(ws + 1052688);       // 4 KB
    int*            cursor   = (int*)(ws + 1056784);         // 4 KB
    int*            flags    = (int*)(ws + 1060880);         // 512 KB
    int*            order    = (int*)(ws + 1585168);         // 512 KB
    unsigned short* eh       = (unsigned short*)(ws + 2109456); // 128 KB
    unsigned short* el       = (unsigned short*)(ws + 2240528); // 128 KB
    float*          rsmo     = (float*)(ws + 2371600);       // 4 KB (end ~2.38 MB)

    // zero esum + hist + nflag + done_cnt + loss_acc (contiguous 786432..1052688)
    hipMemsetAsync(ws + 786432, 0, 266256, stream);

    vq_prep<<<2048, 256, 0, stream>>>(z, zh, zl);
    vq_eprep<<<4, 256, 0, stream>>>(emb, eh, el, halfnorm);
    vq_screen_mfma<<<1024, 256, 0, stream>>>(zh, zl, eh, el, halfnorm,
                                             idx_ws, ind_out, nflag, flags);
    vq_fallback<<<128, 256, 0, stream>>>(z, emb, idx_ws, ind_out, nflag, flags);
    vq_hist<<<64, 256, 0, stream>>>(idx_ws, hist);
    vq_prefix_smo<<<1, 1024, 0, stream>>>(hist, cs, cursor, rsmo);
    vq_scatter<<<N_PTS / 256, 256, 0, stream>>>(idx_ws, cursor, order);
    vq_esum2<<<N_PTS / 256, 256, 0, stream>>>(zh, zl, idx_ws, order, esum);
    vq_newE<<<256, 256, 0, stream>>>(avg, esum, rsmo, newE);
    vq_gather_loss<<<N_PTS / 256, 256, 0, stream>>>(z, newE, idx_ws, zq_out,
                                                    loss_acc, done_cnt, loss_out);
}